// Round 3
// baseline (288.748 us; speedup 1.0000x reference)
//
#include <hip/hip_runtime.h>
#include <stdint.h>
#include <math.h>

// Algebra (validated R3-R7 + re-derivation):
//   q = x0 @ Wq + bq                       (bk is softmax-invariant, dropped)
//   r[h][d]   = sum_c q[h*64+c] * Wk[d][h*64+c]       (no transpose needed)
//   logits[h][n] = (r[h] . x[n]) / 8
//   p = softmax_n ; y[h] = sum_n p[h][n] x[n]          (512-dim per head)
//   ctx[h*64+u] = sum_d y[h][d] Wv[d][h*64+u] + bv     (sum_n p = 1)
//   out = ctx @ Wo + bo
// R10/R11: EVERYTHING fused into one kernel, one block per bs (grid 256 x 512 thr).
//   - all intermediates live in LDS/registers (no q/r/L/Y/ctx global round-trips)
//   - x read ONCE via 32-row LDS tiles + online softmax (was 2 full passes)
//   - weights stream from L2 (1 MiB each, hot across 256 blocks)
//   - 1 launch instead of 5
// (R11 = R10 resubmitted: two consecutive GPU-acquisition timeouts, never benched)

#define NT 32  // x-tile rows per online-softmax step (8 tiles of 32 = 256)

__global__ __launch_bounds__(512) void fused_kernel(
    const float* __restrict__ x,
    const float* __restrict__ Wq, const float* __restrict__ bq,
    const float* __restrict__ Wk,
    const float* __restrict__ Wv, const float* __restrict__ bv,
    const float* __restrict__ Wo, const float* __restrict__ bo,
    float* __restrict__ out) {
  const int bs = blockIdx.x;
  const int t = threadIdx.x;
  const int w = t >> 6, lane = t & 63;
  const float* xb = x + (long)bs * 131072;  // x[bs][n][d], 256*512

  __shared__ float x_tile[NT * 512];   // 64 KB
  __shared__ float r_s[4096];          // 16 KB
  __shared__ float y_s[8 * 520];       // 16.25 KB (stride 520: banks differ per head)
  __shared__ float q_s[512];
  __shared__ float x0_s[512];
  __shared__ float ctx_s[512];
  __shared__ float red_s[3][512];      // 6 KB, k-split reduction scratch
  __shared__ float pt_s[8][NT];        // 1 KB, per-tile scaled probabilities
  __shared__ float f_s[8], s_s[8];

  // ---- stage cls row ----
  if (t < 128) *(float4*)&x0_s[t * 4] = *(const float4*)&xb[t * 4];
  __syncthreads();

  // ---- P0: q = x0 @ Wq + bq (4-way k-split, float4 outputs) ----
  {
    const int j4 = (t & 127) * 4;
    const int kq = t >> 7;  // k quarter 0..3
    float4 a = make_float4(0.f, 0.f, 0.f, 0.f);
    const float* wp = Wq + (long)(kq * 128) * 512 + j4;
    const float* ap = &x0_s[kq * 128];
#pragma unroll 8
    for (int k = 0; k < 128; ++k) {
      float4 wv = *(const float4*)&wp[(long)k * 512];
      float av = ap[k];
      a.x += av * wv.x; a.y += av * wv.y; a.z += av * wv.z; a.w += av * wv.w;
    }
    if (kq > 0) *(float4*)&red_s[kq - 1][j4] = a;
    __syncthreads();
    if (kq == 0) {
#pragma unroll
      for (int rr = 0; rr < 3; ++rr) {
        float4 b = *(const float4*)&red_s[rr][j4];
        a.x += b.x; a.y += b.y; a.z += b.z; a.w += b.w;
      }
      float4 bb = *(const float4*)&bq[j4];
      a.x += bb.x; a.y += bb.y; a.z += bb.z; a.w += bb.w;
      *(float4*)&q_s[j4] = a;
    }
  }
  __syncthreads();

  // ---- P1: r[h*512+t] = sum_c q_s[h*64+c] * Wk[t*512 + h*64+c] ----
  // thread t scans row t of Wk (contiguous per lane -> L1-friendly; Wk is L2-hot)
  {
    const float* wrow = Wk + (long)t * 512;
    for (int h = 0; h < 8; ++h) {
      float racc = 0.f;
      const float* qp = &q_s[h * 64];
#pragma unroll
      for (int c4 = 0; c4 < 16; ++c4) {
        float4 wv = *(const float4*)&wrow[h * 64 + c4 * 4];
        racc += qp[c4 * 4 + 0] * wv.x + qp[c4 * 4 + 1] * wv.y +
                qp[c4 * 4 + 2] * wv.z + qp[c4 * 4 + 3] * wv.w;
      }
      r_s[h * 512 + t] = racc;
    }
  }
  __syncthreads();

  // ---- load r fragments (every wave needs all heads for its logit rows) ----
  float rv[8][8];
#pragma unroll
  for (int h = 0; h < 8; ++h) {
    float4 a = *(const float4*)&r_s[h * 512 + lane * 8];
    float4 b = *(const float4*)&r_s[h * 512 + lane * 8 + 4];
    rv[h][0] = a.x; rv[h][1] = a.y; rv[h][2] = a.z; rv[h][3] = a.w;
    rv[h][4] = b.x; rv[h][5] = b.y; rv[h][6] = b.z; rv[h][7] = b.w;
  }

  // ---- online-softmax state ----
  float accy[8] = {0.f, 0.f, 0.f, 0.f, 0.f, 0.f, 0.f, 0.f};  // y[h][d=t]
  float m_h = -INFINITY, s_h = 0.f;  // wave w tracks head w (lanes<32 valid)
  const int l4 = lane & 4, l2 = lane & 2, l1 = lane & 1;

  for (int tile = 0; tile < 8; ++tile) {
    // stage 32 rows of x into LDS (linear, conflict-free)
    {
      const float* src = xb + (long)tile * NT * 512;
#pragma unroll
      for (int i = 0; i < 8; ++i) {
        int f4 = t + i * 512;  // float4 units, 0..4095
        *(float4*)&x_tile[f4 * 4] = *(const float4*)&src[f4 * 4];
      }
    }
    __syncthreads();

    // logits: wave w computes rows w*4 .. w*4+3 of this tile
#pragma unroll
    for (int i = 0; i < 4; ++i) {
      const int nl = w * 4 + i;
      const float* xr = &x_tile[nl * 512 + lane * 8];
      float4 xa = *(const float4*)xr;
      float4 xb4 = *(const float4*)(xr + 4);
      float acc[8];
#pragma unroll
      for (int h = 0; h < 8; ++h)
        acc[h] = xa.x * rv[h][0] + xa.y * rv[h][1] + xa.z * rv[h][2] + xa.w * rv[h][3]
               + xb4.x * rv[h][4] + xb4.y * rv[h][5] + xb4.z * rv[h][6] + xb4.w * rv[h][7];
#pragma unroll
      for (int j = 0; j < 4; ++j) {
        float v = l4 ? acc[j] : acc[j + 4];
        float tt = __shfl_xor(v, 4);
        acc[j] = (l4 ? acc[j + 4] : acc[j]) + tt;
      }
#pragma unroll
      for (int j = 0; j < 2; ++j) {
        float v = l2 ? acc[j] : acc[j + 2];
        float tt = __shfl_xor(v, 2);
        acc[j] = (l2 ? acc[j + 2] : acc[j]) + tt;
      }
      {
        float v = l1 ? acc[0] : acc[1];
        float tt = __shfl_xor(v, 1);
        acc[0] = (l1 ? acc[1] : acc[0]) + tt;
      }
      acc[0] += __shfl_xor(acc[0], 8);
      acc[0] += __shfl_xor(acc[0], 16);
      acc[0] += __shfl_xor(acc[0], 32);
      if (lane < 8) pt_s[lane][nl] = acc[0] * 0.125f;
    }
    __syncthreads();

    // online-softmax update: wave w owns head w (lanes 0..31 hold the 32 logits)
    {
      float l = (lane < 32) ? pt_s[w][lane] : -INFINITY;
      float tm = l;
#pragma unroll
      for (int o = 16; o; o >>= 1) tm = fmaxf(tm, __shfl_xor(tm, o));
      float m_new = fmaxf(m_h, tm);
      float e = __expf(l - m_new);  // lanes>=32: exp(-inf)=0
      float ts = e;
#pragma unroll
      for (int o = 16; o; o >>= 1) ts += __shfl_xor(ts, o);
      float f = __expf(m_h - m_new);  // first tile: exp(-inf)=0
      s_h = s_h * f + ts;
      m_h = m_new;
      if (lane == 0) f_s[w] = f;
      if (lane < 32) pt_s[w][lane] = e;
    }
    __syncthreads();

    // y accumulate: thread owns d = t; rescale then add tile contribution
    {
#pragma unroll
      for (int h = 0; h < 8; ++h) accy[h] *= f_s[h];
#pragma unroll 4
      for (int n4 = 0; n4 < 8; ++n4) {
        float xv0 = x_tile[(n4 * 4 + 0) * 512 + t];
        float xv1 = x_tile[(n4 * 4 + 1) * 512 + t];
        float xv2 = x_tile[(n4 * 4 + 2) * 512 + t];
        float xv3 = x_tile[(n4 * 4 + 3) * 512 + t];
#pragma unroll
        for (int h = 0; h < 8; ++h) {
          float4 p4 = *(const float4*)&pt_s[h][n4 * 4];
          accy[h] += p4.x * xv0 + p4.y * xv1 + p4.z * xv2 + p4.w * xv3;
        }
      }
    }
    __syncthreads();  // protect x_tile before next stage
  }

  // ---- finalize y ----
  if (lane == 0) s_s[w] = s_h;  // wave w wrote head w's running sum
  __syncthreads();
#pragma unroll
  for (int h = 0; h < 8; ++h) y_s[h * 520 + t] = accy[h] * (1.f / s_s[h]);
  __syncthreads();

  // ---- P5: ctx[o] = sum_d y[h(o)][d] * Wv[d*512+o] + bv[o] (4-way k-split) ----
  {
    const int o4 = (t & 127) * 4;
    const int kq = t >> 7;
    const int h0 = o4 >> 6;  // o4..o4+3 stay within one head block
    float4 a = make_float4(0.f, 0.f, 0.f, 0.f);
    const float* wp = Wv + (long)(kq * 128) * 512 + o4;
    const float* yp = &y_s[h0 * 520 + kq * 128];
#pragma unroll 8
    for (int k = 0; k < 128; ++k) {
      float4 wv = *(const float4*)&wp[(long)k * 512];
      float yv = yp[k];
      a.x += yv * wv.x; a.y += yv * wv.y; a.z += yv * wv.z; a.w += yv * wv.w;
    }
    if (kq > 0) *(float4*)&red_s[kq - 1][o4] = a;
    __syncthreads();
    if (kq == 0) {
#pragma unroll
      for (int rr = 0; rr < 3; ++rr) {
        float4 b = *(const float4*)&red_s[rr][o4];
        a.x += b.x; a.y += b.y; a.z += b.z; a.w += b.w;
      }
      float4 bb = *(const float4*)&bv[o4];
      a.x += bb.x; a.y += bb.y; a.z += bb.z; a.w += bb.w;
      *(float4*)&ctx_s[o4] = a;
    }
  }
  __syncthreads();

  // ---- P6: out = ctx @ Wo + bo (4-way k-split) ----
  {
    const int j4 = (t & 127) * 4;
    const int kq = t >> 7;
    float4 a = make_float4(0.f, 0.f, 0.f, 0.f);
    const float* wp = Wo + (long)(kq * 128) * 512 + j4;
    const float* cp = &ctx_s[kq * 128];
#pragma unroll 8
    for (int k = 0; k < 128; ++k) {
      float4 wv = *(const float4*)&wp[(long)k * 512];
      float cv = cp[k];
      a.x += cv * wv.x; a.y += cv * wv.y; a.z += cv * wv.z; a.w += cv * wv.w;
    }
    if (kq > 0) *(float4*)&red_s[kq - 1][j4] = a;
    __syncthreads();
    if (kq == 0) {
#pragma unroll
      for (int rr = 0; rr < 3; ++rr) {
        float4 b = *(const float4*)&red_s[rr][j4];
        a.x += b.x; a.y += b.y; a.z += b.z; a.w += b.w;
      }
      float4 bb = *(const float4*)&bo[j4];
      a.x += bb.x; a.y += bb.y; a.z += bb.z; a.w += bb.w;
      *(float4*)&out[(long)bs * 512 + j4] = a;
    }
  }
}

extern "C" void kernel_launch(void* const* d_in, const int* in_sizes, int n_in,
                              void* d_out, int out_size, void* d_ws, size_t ws_size,
                              hipStream_t stream) {
  (void)in_sizes; (void)n_in; (void)out_size; (void)d_ws; (void)ws_size;
  const float* x  = (const float*)d_in[0];
  const float* Wq = (const float*)d_in[1];
  const float* bq = (const float*)d_in[2];
  const float* Wk = (const float*)d_in[3];
  // d_in[4] = bk: softmax-invariant, unused
  const float* Wv = (const float*)d_in[5];
  const float* bv = (const float*)d_in[6];
  const float* Wo = (const float*)d_in[7];
  const float* bo = (const float*)d_in[8];
  float* out = (float*)d_out;

  fused_kernel<<<256, 512, 0, stream>>>(x, Wq, bq, Wk, Wv, bv, Wo, bo, out);
}

// Round 4
// 283.369 us; speedup vs baseline: 1.0190x; 1.0190x over previous
//
#include <hip/hip_runtime.h>
#include <stdint.h>
#include <math.h>

// Algebra (validated R3-R7):
//   q = x0 @ Wq + bq                       (bk is softmax-invariant, dropped)
//   r[h][d]   = sum_c q[h*64+c] * Wk[d][h*64+c]       (no transpose needed)
//   logits[h][n] = (r[h] . x[n]) / 8
//   p = softmax_n ; y[h] = sum_n p[h][n] x[n]
//   ctx[h*64+u] = sum_d y[h][d] Wv[d][h*64+u] + bv
//   out = ctx @ Wo + bo
// R12: R10's single fused kernel was latency-bound (VALUBusy 20%, occ 23%,
// HBM 6.6%). This round: 1024 threads (16 waves/CU, was 8), x-tile
// double-buffer (NT=16, 2x32KB) with reg-staged async split: next tile's
// global loads issued before logits, LDS-written after softmax barrier.
// Tile-0 loads hide under the q/r weight phases.

#define NT 16  // x rows per tile; 16 tiles of 16 = 256

__global__ __launch_bounds__(1024) void fused_kernel(
    const float* __restrict__ x,
    const float* __restrict__ Wq, const float* __restrict__ bq,
    const float* __restrict__ Wk,
    const float* __restrict__ Wv, const float* __restrict__ bv,
    const float* __restrict__ Wo, const float* __restrict__ bo,
    float* __restrict__ out) {
  const int bs = blockIdx.x;
  const int t = threadIdx.x;
  const int w = t >> 6, lane = t & 63;
  const float* xb = x + (long)bs * 131072;  // x[bs][n][d], 256*512

  __shared__ float xt[2][NT * 512];    // 64 KB (double-buffered x tiles)
  __shared__ float r_s[4096];          // 16 KB
  __shared__ float y_s[8 * 520];       // 16.6 KB
  __shared__ float ypar[8][512];       // 16 KB (y half-combine)
  __shared__ float red_s[7][512];      // 14 KB (8-way k-split reduce)
  __shared__ float q_s[512];
  __shared__ float x0_s[512];
  __shared__ float ctx_s[512];
  __shared__ float pt_s[8][NT];        // per-tile probabilities
  __shared__ float f_s[8], s_s[8];

  // ---- prologue: stage cls row; issue tile-0 loads (hide under P0/P1) ----
  if (t < 128) *(float4*)&x0_s[t * 4] = *(const float4*)&xb[t * 4];
  float4 st0 = *(const float4*)&xb[(long)t * 4];
  float4 st1 = *(const float4*)&xb[(long)(t + 1024) * 4];
  __syncthreads();

  // ---- P0: q = x0 @ Wq + bq (8-way k-split over 1024 threads) ----
  {
    const int j4 = (t & 127) * 4;
    const int kq = t >> 7;  // 0..7, 64 k's each
    float4 a = make_float4(0.f, 0.f, 0.f, 0.f);
    const float* wp = Wq + (long)(kq * 64) * 512 + j4;
    const float* ap = &x0_s[kq * 64];
#pragma unroll 8
    for (int k = 0; k < 64; ++k) {
      float4 wv = *(const float4*)&wp[(long)k * 512];
      float av = ap[k];
      a.x += av * wv.x; a.y += av * wv.y; a.z += av * wv.z; a.w += av * wv.w;
    }
    if (kq > 0) *(float4*)&red_s[kq - 1][j4] = a;
    __syncthreads();
    if (kq == 0) {
#pragma unroll
      for (int rr = 0; rr < 7; ++rr) {
        float4 b = *(const float4*)&red_s[rr][j4];
        a.x += b.x; a.y += b.y; a.z += b.z; a.w += b.w;
      }
      float4 bb = *(const float4*)&bq[j4];
      a.x += bb.x; a.y += bb.y; a.z += bb.z; a.w += bb.w;
      *(float4*)&q_s[j4] = a;
    }
  }
  __syncthreads();

  // ---- P1: r[h][d]; thread t -> row d = t>>1, heads (t&1)*4..+3 ----
  {
    const int d = t >> 1, hh = t & 1;
    const float* wrow = Wk + (long)d * 512 + hh * 256;
#pragma unroll
    for (int hi = 0; hi < 4; ++hi) {
      const int h = hh * 4 + hi;
      const float* qp = &q_s[h * 64];
      float racc = 0.f;
#pragma unroll
      for (int c4 = 0; c4 < 16; ++c4) {
        float4 wv = *(const float4*)&wrow[hi * 64 + c4 * 4];
        racc += qp[c4 * 4 + 0] * wv.x + qp[c4 * 4 + 1] * wv.y +
                qp[c4 * 4 + 2] * wv.z + qp[c4 * 4 + 3] * wv.w;
      }
      r_s[h * 512 + d] = racc;
    }
  }
  // write tile 0 into buf 0 (vmcnt wait happens here; loads issued long ago)
  *(float4*)&xt[0][t * 4] = st0;
  *(float4*)&xt[0][(t + 1024) * 4] = st1;
  __syncthreads();

  // ---- r fragments to registers ----
  float rv[8][8];
#pragma unroll
  for (int h = 0; h < 8; ++h) {
    float4 a = *(const float4*)&r_s[h * 512 + lane * 8];
    float4 b = *(const float4*)&r_s[h * 512 + lane * 8 + 4];
    rv[h][0] = a.x; rv[h][1] = a.y; rv[h][2] = a.z; rv[h][3] = a.w;
    rv[h][4] = b.x; rv[h][5] = b.y; rv[h][6] = b.z; rv[h][7] = b.w;
  }

  // ---- online-softmax state ----
  float accy[8] = {0.f, 0.f, 0.f, 0.f, 0.f, 0.f, 0.f, 0.f};
  float m_h = -INFINITY, s_h = 0.f;  // wave w<8 tracks head w (lanes<16 active)
  const int l4 = lane & 4, l2 = lane & 2, l1 = lane & 1;
  const int dcol = t & 511, halfn = t >> 9;

  for (int tile = 0; tile < 16; ++tile) {
    const int cur = tile & 1;
    // issue next tile's global loads (latency hides under logits+softmax)
    float4 n0, n1;
    if (tile < 15) {
      const float* src = xb + (long)(tile + 1) * NT * 512;
      n0 = *(const float4*)&src[(long)t * 4];
      n1 = *(const float4*)&src[(long)(t + 1024) * 4];
    }

    // logits: wave w computes row w of this tile (16 waves, 16 rows)
    {
      const float* xr = &xt[cur][w * 512 + lane * 8];
      float4 xa = *(const float4*)xr;
      float4 xb4 = *(const float4*)(xr + 4);
      float acc[8];
#pragma unroll
      for (int h = 0; h < 8; ++h)
        acc[h] = xa.x * rv[h][0] + xa.y * rv[h][1] + xa.z * rv[h][2] + xa.w * rv[h][3]
               + xb4.x * rv[h][4] + xb4.y * rv[h][5] + xb4.z * rv[h][6] + xb4.w * rv[h][7];
#pragma unroll
      for (int j = 0; j < 4; ++j) {
        float v = l4 ? acc[j] : acc[j + 4];
        float tt = __shfl_xor(v, 4);
        acc[j] = (l4 ? acc[j + 4] : acc[j]) + tt;
      }
#pragma unroll
      for (int j = 0; j < 2; ++j) {
        float v = l2 ? acc[j] : acc[j + 2];
        float tt = __shfl_xor(v, 2);
        acc[j] = (l2 ? acc[j + 2] : acc[j]) + tt;
      }
      {
        float v = l1 ? acc[0] : acc[1];
        float tt = __shfl_xor(v, 1);
        acc[0] = (l1 ? acc[1] : acc[0]) + tt;
      }
      acc[0] += __shfl_xor(acc[0], 8);
      acc[0] += __shfl_xor(acc[0], 16);
      acc[0] += __shfl_xor(acc[0], 32);
      if (lane < 8) pt_s[lane][w] = acc[0] * 0.125f;
    }
    __syncthreads();

    // online-softmax update: wave w<8 owns head w; lanes 0..15 hold the tile
    if (w < 8) {
      float l = (lane < 16) ? pt_s[w][lane] : -3.0e38f;
      float tm = l;
#pragma unroll
      for (int o = 8; o; o >>= 1) tm = fmaxf(tm, __shfl_xor(tm, o));
      float m_new = fmaxf(m_h, tm);
      float e = __expf(l - m_new);
      float ts = e;
#pragma unroll
      for (int o = 8; o; o >>= 1) ts += __shfl_xor(ts, o);
      float f = __expf(m_h - m_new);  // tile 0: exp(-inf)=0
      s_h = s_h * f + ts;
      m_h = m_new;
      if (lane == 0) f_s[w] = f;
      if (lane < 16) pt_s[w][lane] = e;
    }
    __syncthreads();

    // write next tile into the idle buffer (no one reads buf[cur^1] now)
    if (tile < 15) {
      *(float4*)&xt[cur ^ 1][t * 4] = n0;
      *(float4*)&xt[cur ^ 1][(t + 1024) * 4] = n1;
    }

    // y accumulate: thread owns d=dcol, n-half halfn (8 n's per tile)
    {
#pragma unroll
      for (int h = 0; h < 8; ++h) accy[h] *= f_s[h];
#pragma unroll
      for (int n4 = 0; n4 < 2; ++n4) {
        const int nb = halfn * 8 + n4 * 4;
        float xv0 = xt[cur][(nb + 0) * 512 + dcol];
        float xv1 = xt[cur][(nb + 1) * 512 + dcol];
        float xv2 = xt[cur][(nb + 2) * 512 + dcol];
        float xv3 = xt[cur][(nb + 3) * 512 + dcol];
#pragma unroll
        for (int h = 0; h < 8; ++h) {
          float4 p4 = *(const float4*)&pt_s[h][nb];
          accy[h] += p4.x * xv0 + p4.y * xv1 + p4.z * xv2 + p4.w * xv3;
        }
      }
    }
    __syncthreads();  // y reads + stage writes done -> next tile
  }

  // ---- finalize y: combine n-halves, normalize ----
  if (w < 8 && lane == 0) s_s[w] = s_h;
  __syncthreads();
  if (halfn == 1) {
#pragma unroll
    for (int h = 0; h < 8; ++h) ypar[h][dcol] = accy[h];
  }
  __syncthreads();
  if (halfn == 0) {
#pragma unroll
    for (int h = 0; h < 8; ++h)
      y_s[h * 520 + dcol] = (accy[h] + ypar[h][dcol]) * (1.f / s_s[h]);
  }
  __syncthreads();

  // ---- P5: ctx[o] = sum_d y[h(o)][d] * Wv[d][o] + bv (8-way k-split) ----
  {
    const int o4 = (t & 127) * 4;
    const int kq = t >> 7;
    const int h0 = o4 >> 6;
    float4 a = make_float4(0.f, 0.f, 0.f, 0.f);
    const float* wp = Wv + (long)(kq * 64) * 512 + o4;
    const float* yp2 = &y_s[h0 * 520 + kq * 64];
#pragma unroll 8
    for (int k = 0; k < 64; ++k) {
      float4 wv = *(const float4*)&wp[(long)k * 512];
      float yv = yp2[k];
      a.x += yv * wv.x; a.y += yv * wv.y; a.z += yv * wv.z; a.w += yv * wv.w;
    }
    if (kq > 0) *(float4*)&red_s[kq - 1][o4] = a;
    __syncthreads();
    if (kq == 0) {
#pragma unroll
      for (int rr = 0; rr < 7; ++rr) {
        float4 b = *(const float4*)&red_s[rr][o4];
        a.x += b.x; a.y += b.y; a.z += b.z; a.w += b.w;
      }
      float4 bb = *(const float4*)&bv[o4];
      a.x += bb.x; a.y += bb.y; a.z += bb.z; a.w += bb.w;
      *(float4*)&ctx_s[o4] = a;
    }
  }
  __syncthreads();

  // ---- P6: out = ctx @ Wo + bo (8-way k-split) ----
  {
    const int j4 = (t & 127) * 4;
    const int kq = t >> 7;
    float4 a = make_float4(0.f, 0.f, 0.f, 0.f);
    const float* wp = Wo + (long)(kq * 64) * 512 + j4;
    const float* cp = &ctx_s[kq * 64];
#pragma unroll 8
    for (int k = 0; k < 64; ++k) {
      float4 wv = *(const float4*)&wp[(long)k * 512];
      float cv = cp[k];
      a.x += cv * wv.x; a.y += cv * wv.y; a.z += cv * wv.z; a.w += cv * wv.w;
    }
    if (kq > 0) *(float4*)&red_s[kq - 1][j4] = a;
    __syncthreads();
    if (kq == 0) {
#pragma unroll
      for (int rr = 0; rr < 7; ++rr) {
        float4 b = *(const float4*)&red_s[rr][j4];
        a.x += b.x; a.y += b.y; a.z += b.z; a.w += b.w;
      }
      float4 bb = *(const float4*)&bo[j4];
      a.x += bb.x; a.y += bb.y; a.z += bb.z; a.w += bb.w;
      *(float4*)&out[(long)bs * 512 + j4] = a;
    }
  }
}

extern "C" void kernel_launch(void* const* d_in, const int* in_sizes, int n_in,
                              void* d_out, int out_size, void* d_ws, size_t ws_size,
                              hipStream_t stream) {
  (void)in_sizes; (void)n_in; (void)out_size; (void)d_ws; (void)ws_size;
  const float* x  = (const float*)d_in[0];
  const float* Wq = (const float*)d_in[1];
  const float* bq = (const float*)d_in[2];
  const float* Wk = (const float*)d_in[3];
  // d_in[4] = bk: softmax-invariant, unused
  const float* Wv = (const float*)d_in[5];
  const float* bv = (const float*)d_in[6];
  const float* Wo = (const float*)d_in[7];
  const float* bo = (const float*)d_in[8];
  float* out = (float*)d_out;

  fused_kernel<<<256, 1024, 0, stream>>>(x, Wq, bq, Wk, Wv, bv, Wo, bo, out);
}

// Round 5
// 280.276 us; speedup vs baseline: 1.0302x; 1.0110x over previous
//
#include <hip/hip_runtime.h>
#include <stdint.h>
#include <math.h>

// Algebra (validated R3-R7):
//   q = x0 @ Wq + bq                       (bk is softmax-invariant, dropped)
//   r[h][d]   = sum_c q[h*64+c] * Wk[d][h*64+c]       (no transpose needed)
//   logits[h][n] = (r[h] . x[n]) / 8
//   p = softmax_n ; y[h] = sum_n p[h][n] x[n]
//   ctx[h*64+u] = sum_d y[h][d] Wv[d][h*64+u] + bv
//   out = ctx @ Wo + bo
// R12: fused kernel, 1024 thr, x double-buffer. 137us, but VGPR_Count=64
// (compiler cap, no min-waves hint) forced spills: WRITE_SIZE 6.6MB >> 0.5MB
// output. R13 (this round):
//   - __launch_bounds__(1024, 4): 16 waves/CU declared -> 128 VGPR budget
//   - logits split 2 waves/row x 4 heads (rv[4][8]=32 regs, was 64); each
//     wave does 2 rows/tile (independent reduce chains -> ILP)

#define NT 16  // x rows per tile; 16 tiles of 16 = 256

__global__ __launch_bounds__(1024, 4) void fused_kernel(
    const float* __restrict__ x,
    const float* __restrict__ Wq, const float* __restrict__ bq,
    const float* __restrict__ Wk,
    const float* __restrict__ Wv, const float* __restrict__ bv,
    const float* __restrict__ Wo, const float* __restrict__ bo,
    float* __restrict__ out) {
  const int bs = blockIdx.x;
  const int t = threadIdx.x;
  const int w = t >> 6, lane = t & 63;
  const float* xb = x + (long)bs * 131072;  // x[bs][n][d], 256*512

  __shared__ float xt[2][NT * 512];    // 64 KB (double-buffered x tiles)
  __shared__ float r_s[4096];          // 16 KB
  __shared__ float y_s[8 * 520];       // 16.6 KB
  __shared__ float ypar[8][512];       // 16 KB (y half-combine)
  __shared__ float red_s[7][512];      // 14 KB (8-way k-split reduce)
  __shared__ float q_s[512];
  __shared__ float x0_s[512];
  __shared__ float ctx_s[512];
  __shared__ float pt_s[8][NT];        // per-tile probabilities
  __shared__ float f_s[8], s_s[8];

  // ---- prologue: stage cls row; issue tile-0 loads (hide under P0/P1) ----
  if (t < 128) *(float4*)&x0_s[t * 4] = *(const float4*)&xb[t * 4];
  float4 st0 = *(const float4*)&xb[(long)t * 4];
  float4 st1 = *(const float4*)&xb[(long)(t + 1024) * 4];
  __syncthreads();

  // ---- P0: q = x0 @ Wq + bq (8-way k-split over 1024 threads) ----
  {
    const int j4 = (t & 127) * 4;
    const int kq = t >> 7;  // 0..7, 64 k's each
    float4 a = make_float4(0.f, 0.f, 0.f, 0.f);
    const float* wp = Wq + (long)(kq * 64) * 512 + j4;
    const float* ap = &x0_s[kq * 64];
#pragma unroll 8
    for (int k = 0; k < 64; ++k) {
      float4 wv = *(const float4*)&wp[(long)k * 512];
      float av = ap[k];
      a.x += av * wv.x; a.y += av * wv.y; a.z += av * wv.z; a.w += av * wv.w;
    }
    if (kq > 0) *(float4*)&red_s[kq - 1][j4] = a;
    __syncthreads();
    if (kq == 0) {
#pragma unroll
      for (int rr = 0; rr < 7; ++rr) {
        float4 b = *(const float4*)&red_s[rr][j4];
        a.x += b.x; a.y += b.y; a.z += b.z; a.w += b.w;
      }
      float4 bb = *(const float4*)&bq[j4];
      a.x += bb.x; a.y += bb.y; a.z += bb.z; a.w += bb.w;
      *(float4*)&q_s[j4] = a;
    }
  }
  __syncthreads();

  // ---- P1: r[h][d]; thread t -> row d = t>>1, heads (t&1)*4..+3 ----
  {
    const int d = t >> 1, hh = t & 1;
    const float* wrow = Wk + (long)d * 512 + hh * 256;
#pragma unroll
    for (int hi = 0; hi < 4; ++hi) {
      const int h = hh * 4 + hi;
      const float* qp = &q_s[h * 64];
      float racc = 0.f;
#pragma unroll
      for (int c4 = 0; c4 < 16; ++c4) {
        float4 wv = *(const float4*)&wrow[hi * 64 + c4 * 4];
        racc += qp[c4 * 4 + 0] * wv.x + qp[c4 * 4 + 1] * wv.y +
                qp[c4 * 4 + 2] * wv.z + qp[c4 * 4 + 3] * wv.w;
      }
      r_s[h * 512 + d] = racc;
    }
  }
  // write tile 0 into buf 0 (vmcnt wait here; loads issued in prologue)
  *(float4*)&xt[0][t * 4] = st0;
  *(float4*)&xt[0][(t + 1024) * 4] = st1;
  __syncthreads();

  // ---- r fragments: wave w loads only its head group (4 heads, 32 regs) ----
  const int hg = w & 1;        // head group: heads hg*4 .. hg*4+3
  const int rw = w >> 1;       // row-within-pass 0..7
  float rv[4][8];
#pragma unroll
  for (int hi = 0; hi < 4; ++hi) {
    const int h = hg * 4 + hi;
    float4 a = *(const float4*)&r_s[h * 512 + lane * 8];
    float4 b = *(const float4*)&r_s[h * 512 + lane * 8 + 4];
    rv[hi][0] = a.x; rv[hi][1] = a.y; rv[hi][2] = a.z; rv[hi][3] = a.w;
    rv[hi][4] = b.x; rv[hi][5] = b.y; rv[hi][6] = b.z; rv[hi][7] = b.w;
  }

  // ---- online-softmax state ----
  float accy[8] = {0.f, 0.f, 0.f, 0.f, 0.f, 0.f, 0.f, 0.f};
  float m_h = -INFINITY, s_h = 0.f;  // wave w<8 tracks head w (lanes<16 active)
  const int dcol = t & 511, halfn = t >> 9;

  for (int tile = 0; tile < 16; ++tile) {
    const int cur = tile & 1;
    // issue next tile's global loads (latency hides under logits+softmax)
    float4 n0, n1;
    if (tile < 15) {
      const float* src = xb + (long)(tile + 1) * NT * 512;
      n0 = *(const float4*)&src[(long)t * 4];
      n1 = *(const float4*)&src[(long)(t + 1024) * 4];
    }

    // logits: 2 waves per row (head groups), 2 rows per wave (ILP)
#pragma unroll
    for (int pass = 0; pass < 2; ++pass) {
      const int row = pass * 8 + rw;
      const float* xr = &xt[cur][row * 512 + lane * 8];
      float4 xa = *(const float4*)xr;
      float4 xb4 = *(const float4*)(xr + 4);
      float acc[4];
#pragma unroll
      for (int hi = 0; hi < 4; ++hi)
        acc[hi] = xa.x * rv[hi][0] + xa.y * rv[hi][1] + xa.z * rv[hi][2] + xa.w * rv[hi][3]
                + xb4.x * rv[hi][4] + xb4.y * rv[hi][5] + xb4.z * rv[hi][6] + xb4.w * rv[hi][7];
#pragma unroll
      for (int j = 0; j < 2; ++j) {
        float v = (lane & 2) ? acc[j] : acc[j + 2];
        float tt = __shfl_xor(v, 2);
        acc[j] = ((lane & 2) ? acc[j + 2] : acc[j]) + tt;
      }
      {
        float v = (lane & 1) ? acc[0] : acc[1];
        float tt = __shfl_xor(v, 1);
        acc[0] = ((lane & 1) ? acc[1] : acc[0]) + tt;
      }
      acc[0] += __shfl_xor(acc[0], 4);
      acc[0] += __shfl_xor(acc[0], 8);
      acc[0] += __shfl_xor(acc[0], 16);
      acc[0] += __shfl_xor(acc[0], 32);
      if (lane < 4) pt_s[hg * 4 + lane][row] = acc[0] * 0.125f;
    }
    __syncthreads();

    // online-softmax update: wave w<8 owns head w; lanes 0..15 hold the tile
    if (w < 8) {
      float l = (lane < 16) ? pt_s[w][lane] : -3.0e38f;
      float tm = l;
#pragma unroll
      for (int o = 8; o; o >>= 1) tm = fmaxf(tm, __shfl_xor(tm, o));
      float m_new = fmaxf(m_h, tm);
      float e = __expf(l - m_new);
      float ts = e;
#pragma unroll
      for (int o = 8; o; o >>= 1) ts += __shfl_xor(ts, o);
      float f = __expf(m_h - m_new);  // tile 0: exp(-inf)=0
      s_h = s_h * f + ts;
      m_h = m_new;
      if (lane == 0) f_s[w] = f;
      if (lane < 16) pt_s[w][lane] = e;
    }
    __syncthreads();

    // write next tile into the idle buffer (no one reads buf[cur^1] now)
    if (tile < 15) {
      *(float4*)&xt[cur ^ 1][t * 4] = n0;
      *(float4*)&xt[cur ^ 1][(t + 1024) * 4] = n1;
    }

    // y accumulate: thread owns d=dcol, n-half halfn (8 n's per tile)
    {
#pragma unroll
      for (int h = 0; h < 8; ++h) accy[h] *= f_s[h];
#pragma unroll
      for (int n4 = 0; n4 < 2; ++n4) {
        const int nb = halfn * 8 + n4 * 4;
        float xv0 = xt[cur][(nb + 0) * 512 + dcol];
        float xv1 = xt[cur][(nb + 1) * 512 + dcol];
        float xv2 = xt[cur][(nb + 2) * 512 + dcol];
        float xv3 = xt[cur][(nb + 3) * 512 + dcol];
#pragma unroll
        for (int h = 0; h < 8; ++h) {
          float4 p4 = *(const float4*)&pt_s[h][nb];
          accy[h] += p4.x * xv0 + p4.y * xv1 + p4.z * xv2 + p4.w * xv3;
        }
      }
    }
    __syncthreads();  // y reads + stage writes done -> next tile
  }

  // ---- finalize y: combine n-halves, normalize ----
  if (w < 8 && lane == 0) s_s[w] = s_h;
  __syncthreads();
  if (halfn == 1) {
#pragma unroll
    for (int h = 0; h < 8; ++h) ypar[h][dcol] = accy[h];
  }
  __syncthreads();
  if (halfn == 0) {
#pragma unroll
    for (int h = 0; h < 8; ++h)
      y_s[h * 520 + dcol] = (accy[h] + ypar[h][dcol]) * (1.f / s_s[h]);
  }
  __syncthreads();

  // ---- P5: ctx[o] = sum_d y[h(o)][d] * Wv[d][o] + bv (8-way k-split) ----
  {
    const int o4 = (t & 127) * 4;
    const int kq = t >> 7;
    const int h0 = o4 >> 6;
    float4 a = make_float4(0.f, 0.f, 0.f, 0.f);
    const float* wp = Wv + (long)(kq * 64) * 512 + o4;
    const float* yp2 = &y_s[h0 * 520 + kq * 64];
#pragma unroll 8
    for (int k = 0; k < 64; ++k) {
      float4 wv = *(const float4*)&wp[(long)k * 512];
      float yv = yp2[k];
      a.x += yv * wv.x; a.y += yv * wv.y; a.z += yv * wv.z; a.w += yv * wv.w;
    }
    if (kq > 0) *(float4*)&red_s[kq - 1][o4] = a;
    __syncthreads();
    if (kq == 0) {
#pragma unroll
      for (int rr = 0; rr < 7; ++rr) {
        float4 b = *(const float4*)&red_s[rr][o4];
        a.x += b.x; a.y += b.y; a.z += b.z; a.w += b.w;
      }
      float4 bb = *(const float4*)&bv[o4];
      a.x += bb.x; a.y += bb.y; a.z += bb.z; a.w += bb.w;
      *(float4*)&ctx_s[o4] = a;
    }
  }
  __syncthreads();

  // ---- P6: out = ctx @ Wo + bo (8-way k-split) ----
  {
    const int j4 = (t & 127) * 4;
    const int kq = t >> 7;
    float4 a = make_float4(0.f, 0.f, 0.f, 0.f);
    const float* wp = Wo + (long)(kq * 64) * 512 + j4;
    const float* cp = &ctx_s[kq * 64];
#pragma unroll 8
    for (int k = 0; k < 64; ++k) {
      float4 wv = *(const float4*)&wp[(long)k * 512];
      float cv = cp[k];
      a.x += cv * wv.x; a.y += cv * wv.y; a.z += cv * wv.z; a.w += cv * wv.w;
    }
    if (kq > 0) *(float4*)&red_s[kq - 1][j4] = a;
    __syncthreads();
    if (kq == 0) {
#pragma unroll
      for (int rr = 0; rr < 7; ++rr) {
        float4 b = *(const float4*)&red_s[rr][j4];
        a.x += b.x; a.y += b.y; a.z += b.z; a.w += b.w;
      }
      float4 bb = *(const float4*)&bo[j4];
      a.x += bb.x; a.y += bb.y; a.z += bb.z; a.w += bb.w;
      *(float4*)&out[(long)bs * 512 + j4] = a;
    }
  }
}

extern "C" void kernel_launch(void* const* d_in, const int* in_sizes, int n_in,
                              void* d_out, int out_size, void* d_ws, size_t ws_size,
                              hipStream_t stream) {
  (void)in_sizes; (void)n_in; (void)out_size; (void)d_ws; (void)ws_size;
  const float* x  = (const float*)d_in[0];
  const float* Wq = (const float*)d_in[1];
  const float* bq = (const float*)d_in[2];
  const float* Wk = (const float*)d_in[3];
  // d_in[4] = bk: softmax-invariant, unused
  const float* Wv = (const float*)d_in[5];
  const float* bv = (const float*)d_in[6];
  const float* Wo = (const float*)d_in[7];
  const float* bo = (const float*)d_in[8];
  float* out = (float*)d_out;

  fused_kernel<<<256, 1024, 0, stream>>>(x, Wq, bq, Wk, Wv, bv, Wo, bo, out);
}